// Round 8
// baseline (46.426 us; speedup 1.0000x reference)
//
#include <hip/hip_runtime.h>
#include <hip/hip_fp16.h>

// CoarseWarp via fp16 channel-last gather (round-5 layout, barrier-free K2):
//   K1: P[b][py][px][c] = (fp16) reflect-pad(ref)[b][c][py][px]   (padded 256x256)
//   K2: out[b][c][y][x] = sum_{i,j} (f32)P[b][i+sy, j+sx, c]
// K2 wave = 16 px x 32 ch (lane = cg[0,4) x pq[0,16)): per tap one uint4/lane,
// 16 px x 64 B = 16 lines per instruction (same as round 5), but NO output
// LDS transpose / second barrier, and stores are full 64B-line nt segments.
// LDS 432 B, ~60 VGPR -> 32 waves/CU: maximize in-flight gather lines.
// Accumulation f32, same i,j order; masked FMA bit-exact vs skip.

#define B_   2
#define C_   64
#define HR_  254
#define WR_  254
#define HO_  256
#define WO_  256
#define L_   (HR_ * WR_)
#define PLANE_ ((size_t)HO_ * WO_ * C_)   // halfs per batch (8.4 MB)

// ---------------- Kernel 1: transpose + reflect-pad to fp16 ----------------
// Block = (b, py, 64-px x-quarter). Coalesced read, fp16 LDS, 128B/px writes.
__global__ __launch_bounds__(256) void pad_transpose_h2(
    const float* __restrict__ ref, _Float16* __restrict__ P)
{
    __shared__ unsigned short srow[C_][66];

    unsigned bid  = blockIdx.x;          // [0, 2048)
    unsigned b    = bid >> 10;
    unsigned rest = bid & 1023u;
    unsigned py   = rest >> 2;
    unsigned x0   = (rest & 3u) * 64u;
    int ry = (py == 0) ? 1 : ((py == HO_ - 1) ? HR_ - 2 : (int)py - 1);

    const float* rrow = ref + ((size_t)b * C_) * (HR_ * WR_) + (size_t)ry * WR_;
    unsigned tid = threadIdx.x;

    #pragma unroll
    for (unsigned k = 0; k < 16; ++k) {
        unsigned e = k * 256u + tid;
        unsigned c = e >> 6, u = e & 63u;
        unsigned px = x0 + u;
        int rx = (px == 0) ? 1 : ((px == WO_ - 1) ? WR_ - 2 : (int)px - 1);
        float v = __builtin_nontemporal_load(&rrow[(size_t)c * (HR_ * WR_) + rx]);
        _Float16 h = (_Float16)v;
        srow[c][u] = __builtin_bit_cast(unsigned short, h);
    }
    __syncthreads();

    _Float16* prow = P + ((size_t)(b * HO_ + py) * WO_ + x0) * C_;
    #pragma unroll
    for (unsigned it = 0; it < 8; ++it) {
        unsigned u2  = it * 256u + tid;
        unsigned cp  = u2 & 31u;               // channel pair [0,32)
        unsigned pxl = u2 >> 5;                // [0,64)
        unsigned pk = (unsigned)srow[2 * cp][pxl]
                    | ((unsigned)srow[2 * cp + 1][pxl] << 16);
        *reinterpret_cast<unsigned*>(prow + (size_t)pxl * C_ + 2 * cp) = pk;
    }
}

// ---------------- Kernel 2: barrier-free batched gather + fold --------------
// Block 256 thr = 4 waves; block = (b, y, 32-px x-segment).
// Wave wv: px-half = wv>>1 (16 px), ch-base = (wv&1)*32 (32 ch).
// lane = (cg in [0,4), pq in [0,16)); 9 uint4 loads in flight per wave.
__global__ __launch_bounds__(256) void warp_gather7_kernel(
    const _Float16* __restrict__ P,
    const int*      __restrict__ index_map,
    float*          __restrict__ out)
{
    __shared__ unsigned sbase[3][36];     // rows y-2..y, cols x0-2 .. x0+33

    // Bijective XCD swizzle: 4096 = 8 * 512.
    unsigned p  = blockIdx.x;
    unsigned wg = (p & 7u) * 512u + (p >> 3);
    unsigned b    = wg >> 11;
    unsigned rest = wg & 2047u;
    unsigned y    = rest >> 3;
    unsigned x0   = (rest & 7u) * 32u;
    unsigned tid  = threadIdx.x;

    const int* imb = index_map + (size_t)b * L_;
    if (tid < 108) {
        unsigned r    = tid / 36;         // row y-2+r  (r = 2-i)
        unsigned ccol = tid - r * 36;
        int ly = (int)y - 2 + (int)r;
        int lx = (int)(x0 + ccol) - 2;
        unsigned v = 0xFFFFFFFFu;
        if (ly >= 0 && ly < HR_ && lx >= 0 && lx < WR_) {
            unsigned src = (unsigned)imb[ly * WR_ + lx];
            unsigned sy  = src / WR_;
            unsigned sx  = src - sy * WR_;
            v = (sy * (unsigned)WO_ + sx) * (unsigned)C_;  // half-elem offset
        }
        sbase[r][ccol] = v;
    }
    __syncthreads();

    unsigned wv   = tid >> 6;
    unsigned lane = tid & 63u;
    unsigned pq   = lane & 15u;           // pixel sub-index [0,16)
    unsigned cg   = lane >> 4;            // 8-ch group [0,4)
    unsigned pxl  = (wv >> 1) * 16u + pq; // local pixel [0,32)
    unsigned chb  = (wv & 1u) * 32u;      // channel base {0,32}
    const _Float16* Pp = P + (size_t)b * PLANE_;

    uint4 raw[9];
    float msk[9];
    #pragma unroll
    for (int k = 0; k < 9; ++k) {
        int i = k / 3, j = k % 3;
        unsigned v = sbase[2 - i][pxl + 2u - (unsigned)j];
        bool valid = (v != 0xFFFFFFFFu);
        unsigned off = (valid ? v : 0u)
                     + (unsigned)((i * WO_ + j) * C_) + chb + cg * 8u;
        msk[k] = valid ? 1.0f : 0.0f;
        raw[k] = *reinterpret_cast<const uint4*>(Pp + off);
    }

    float acc[8] = {0.f, 0.f, 0.f, 0.f, 0.f, 0.f, 0.f, 0.f};
    #pragma unroll
    for (int k = 0; k < 9; ++k) {
        union { uint4 u; _Float16 hh[8]; } cv;
        cv.u = raw[k];
        #pragma unroll
        for (int m = 0; m < 8; ++m) {
            acc[m] = fmaf((float)cv.hh[m], msk[k], acc[m]);
        }
    }

    // Direct nt stores: fixed m -> 4 cg x 16 consecutive px = 4 full 64B lines.
    float* ob = out + ((size_t)b * C_) * (HO_ * WO_) + (size_t)y * WO_ + x0;
    #pragma unroll
    for (int m = 0; m < 8; ++m) {
        unsigned ch = chb + cg * 8u + (unsigned)m;
        __builtin_nontemporal_store(acc[m],
            ob + (size_t)ch * (HO_ * WO_) + pxl);
    }
}

extern "C" void kernel_launch(void* const* d_in, const int* in_sizes, int n_in,
                              void* d_out, int out_size, void* d_ws, size_t ws_size,
                              hipStream_t stream) {
    const float* ref       = (const float*)d_in[1];
    const int*   index_map = (const int*)d_in[2];
    float*       out       = (float*)d_out;

    _Float16* P = (_Float16*)d_ws;   // fully overwritten before use
    pad_transpose_h2<<<dim3(B_ * HO_ * 4), dim3(256), 0, stream>>>(ref, P);
    warp_gather7_kernel<<<dim3(B_ * HO_ * 8), dim3(256), 0, stream>>>(P, index_map, out);
}

// Round 9
// 36.262 us; speedup vs baseline: 1.2803x; 1.2803x over previous
//
#include <hip/hip_runtime.h>
#include <hip/hip_fp16.h>

// CoarseWarp via fp16 channel-last gather (round-5 structure, K1 MLP fix):
//   K1: P[b][py][px][c] = (fp16) reflect-pad(ref)[b][c][py][px]   (padded 256x256)
//   K2: out[b][c][y][x] = sum_{i,j} (f32)P[b][i+sy, j+sx, c]
// K2 (unchanged from round 5, best known): tap = 128 B pixel-vector = one
// cache line; 9 uint4 loads in flight per wave; LDS transpose for 128 B
// coalesced nt output stores. K1: per-thread rx hoisted (loop-invariant),
// 16 channel-plane loads batched into registers (MLP), uint2 P stores.
// Accumulation f32, same i,j order; masked FMA bit-exact vs skip.

#define B_   2
#define C_   64
#define HR_  254
#define WR_  254
#define HO_  256
#define WO_  256
#define L_   (HR_ * WR_)
#define PLANE_ ((size_t)HO_ * WO_ * C_)   // halfs per batch (8.4 MB)

// ---------------- Kernel 1: transpose + reflect-pad to fp16 ----------------
// Block = (b, py, 64-px x-quarter). Phase A: 16 batched global loads / thread
// (thread = fixed px-column u, channel c = 4k + w). Phase B: cvt + LDS.
// Phase C: uint2 blocked stores, 4 px x 128 B segments per wave.
__global__ __launch_bounds__(256) void pad_transpose_h3(
    const float* __restrict__ ref, _Float16* __restrict__ P)
{
    __shared__ unsigned short srow[C_][66];

    unsigned bid  = blockIdx.x;          // [0, 2048)
    unsigned b    = bid >> 10;
    unsigned rest = bid & 1023u;
    unsigned py   = rest >> 2;
    unsigned x0   = (rest & 3u) * 64u;
    int ry = (py == 0) ? 1 : ((py == HO_ - 1) ? HR_ - 2 : (int)py - 1);

    const float* rrow = ref + ((size_t)b * C_) * (HR_ * WR_) + (size_t)ry * WR_;
    unsigned tid = threadIdx.x;
    unsigned u   = tid & 63u;            // px column within tile (fixed)
    unsigned w   = tid >> 6;             // wave id -> channel offset

    unsigned px = x0 + u;
    int rx = (px == 0) ? 1 : ((px == WO_ - 1) ? WR_ - 2 : (int)px - 1);
    const float* colp = rrow + rx;

    float vreg[16];
    #pragma unroll
    for (unsigned k = 0; k < 16; ++k) {
        unsigned c = k * 4u + w;
        vreg[k] = colp[(size_t)c * (HR_ * WR_)];
    }
    #pragma unroll
    for (unsigned k = 0; k < 16; ++k) {
        unsigned c = k * 4u + w;
        _Float16 h = (_Float16)vreg[k];
        srow[c][u] = __builtin_bit_cast(unsigned short, h);
    }
    __syncthreads();

    _Float16* prow = P + ((size_t)(b * HO_ + py) * WO_ + x0) * C_;
    #pragma unroll
    for (unsigned it = 0; it < 4; ++it) {
        unsigned u2  = it * 256u + tid;        // [0, 1024)
        unsigned cpp = u2 & 15u;               // ch quad [0,16): ch 4cpp..4cpp+3
        unsigned pxl = u2 >> 4;                // [0,64)
        unsigned lo = (unsigned)srow[4 * cpp][pxl]
                    | ((unsigned)srow[4 * cpp + 1][pxl] << 16);
        unsigned hi = (unsigned)srow[4 * cpp + 2][pxl]
                    | ((unsigned)srow[4 * cpp + 3][pxl] << 16);
        uint2 pk = make_uint2(lo, hi);
        *reinterpret_cast<uint2*>(prow + (size_t)pxl * C_ + 4 * cpp) = pk;
    }
}

// ---------------- Kernel 2: batched uint4 fp16 gather + fold (round 5) ------
// Block 256 thr = 4 waves; block = (b, y, 32-px x-segment). Wave: 8 px;
// lane = (q in [0,8) pixel, cg in [0,8) 8-channel group); 9 uint4 in flight.
__global__ __launch_bounds__(256) void warp_gather4_kernel(
    const _Float16* __restrict__ P,
    const int*      __restrict__ index_map,
    float*          __restrict__ out)
{
    __shared__ unsigned sbase[3][36];     // rows y-2..y, cols x0-2 .. x0+33
    __shared__ float    slds[32][65];     // [px][ch]

    unsigned bid  = blockIdx.x;           // [0, 4096)
    unsigned b    = bid >> 11;
    unsigned rest = bid & 2047u;
    unsigned y    = rest >> 3;
    unsigned x0   = (rest & 7u) * 32u;
    unsigned tid  = threadIdx.x;

    const int* imb = index_map + (size_t)b * L_;
    if (tid < 108) {
        unsigned r    = tid / 36;         // row y-2+r  (r = 2-i)
        unsigned ccol = tid - r * 36;
        int ly = (int)y - 2 + (int)r;
        int lx = (int)(x0 + ccol) - 2;
        unsigned v = 0xFFFFFFFFu;
        if (ly >= 0 && ly < HR_ && lx >= 0 && lx < WR_) {
            unsigned src = (unsigned)imb[ly * WR_ + lx];
            unsigned sy  = src / WR_;
            unsigned sx  = src - sy * WR_;
            v = (sy * (unsigned)WO_ + sx) * (unsigned)C_;  // half-elem offset
        }
        sbase[r][ccol] = v;
    }
    __syncthreads();

    unsigned wv   = tid >> 6;
    unsigned lane = tid & 63u;
    unsigned q    = lane >> 3;            // pixel sub-index [0,8)
    unsigned cg   = lane & 7u;            // channels 8cg .. 8cg+7
    unsigned pxl  = wv * 8u + q;          // local pixel [0,32)
    const _Float16* Pp = P + (size_t)b * PLANE_;

    uint4 raw[9];
    float msk[9];
    #pragma unroll
    for (int k = 0; k < 9; ++k) {
        int i = k / 3, j = k % 3;
        unsigned v = sbase[2 - i][pxl + 2u - (unsigned)j];
        bool valid = (v != 0xFFFFFFFFu);
        unsigned off = (valid ? v : 0u)
                     + (unsigned)((i * WO_ + j) * C_) + cg * 8u;
        msk[k] = valid ? 1.0f : 0.0f;
        raw[k] = *reinterpret_cast<const uint4*>(Pp + off);
    }

    float acc[8] = {0.f, 0.f, 0.f, 0.f, 0.f, 0.f, 0.f, 0.f};
    #pragma unroll
    for (int k = 0; k < 9; ++k) {
        union { uint4 u; _Float16 h[8]; } cv;
        cv.u = raw[k];
        #pragma unroll
        for (int m = 0; m < 8; ++m) {
            acc[m] = fmaf((float)cv.h[m], msk[k], acc[m]);
        }
    }
    *reinterpret_cast<float4*>(&slds[pxl][cg * 8u]) =
        make_float4(acc[0], acc[1], acc[2], acc[3]);
    *reinterpret_cast<float4*>(&slds[pxl][cg * 8u + 4u]) =
        make_float4(acc[4], acc[5], acc[6], acc[7]);
    __syncthreads();

    // Store: lanes 0..31 = px (128 B contiguous), ch per half-wave; nt stores.
    float* ob = out + ((size_t)b * C_) * (HO_ * WO_) + (size_t)y * WO_ + x0;
    #pragma unroll
    for (unsigned it = 0; it < 8; ++it) {
        unsigned u2 = it * 256u + tid;
        unsigned px = u2 & 31u;
        unsigned ch = u2 >> 5;
        __builtin_nontemporal_store(slds[px][ch],
                                    ob + (size_t)ch * (HO_ * WO_) + px);
    }
}

extern "C" void kernel_launch(void* const* d_in, const int* in_sizes, int n_in,
                              void* d_out, int out_size, void* d_ws, size_t ws_size,
                              hipStream_t stream) {
    const float* ref       = (const float*)d_in[1];
    const int*   index_map = (const int*)d_in[2];
    float*       out       = (float*)d_out;

    _Float16* P = (_Float16*)d_ws;   // fully overwritten before use
    pad_transpose_h3<<<dim3(B_ * HO_ * 4), dim3(256), 0, stream>>>(ref, P);
    warp_gather4_kernel<<<dim3(B_ * HO_ * 8), dim3(256), 0, stream>>>(P, index_map, out);
}